// Round 5
// baseline (212.524 us; speedup 1.0000x reference)
//
#include <hip/hip_runtime.h>
#include <math.h>

#define NHEADS 16
#define HS     128
#define NOPT   512
#define TB     128      // tokens per block (4 waves x 32)
#define OC     32       // options per chunk
#define NCH    16       // chunks
#define EMB    2048
#define LOG2E  1.44269504088896340736f
#define THRD   11.0f    // defer-max threshold (log2 units): P <= 2^11, f32 sum safe

typedef short bf16x8 __attribute__((ext_vector_type(8)));
typedef unsigned short u16x8 __attribute__((ext_vector_type(8)));
typedef float f32x4 __attribute__((ext_vector_type(4)));
typedef float f32x16 __attribute__((ext_vector_type(16)));
typedef unsigned u32x4 __attribute__((ext_vector_type(4)));

__device__ __forceinline__ unsigned short f2bf(float f) {
    union { float f; unsigned u; } v; v.f = f;
    unsigned r = v.u + 0x7FFFu + ((v.u >> 16) & 1u);   // rn-even
    return (unsigned short)(r >> 16);
}
__device__ __forceinline__ float bf2f(unsigned short h) {
    union { unsigned u; float f; } v; v.u = ((unsigned)h) << 16;
    return v.f;
}
__device__ __forceinline__ void gll16(const void* gptr, void* lptr) {
    __builtin_amdgcn_global_load_lds(
        (const __attribute__((address_space(1))) void*)gptr,
        (__attribute__((address_space(3))) void*)lptr,
        16, 0, 0);
}
__device__ __forceinline__ unsigned cvtpk(float lo, float hi) {
    unsigned r;
    asm("v_cvt_pk_bf16_f32 %0, %1, %2" : "=v"(r) : "v"(lo), "v"(hi));
    return r;
}
// v_permlane32_swap_b32: a' = {a.lo, b.lo_old}, b' = {a.hi_old, b.hi}
__device__ __forceinline__ void pl32swap(unsigned &a, unsigned &b) {
    asm volatile("v_permlane32_swap_b32 %0, %1" : "+v"(a), "+v"(b));
}
__device__ __forceinline__ f32x16 mfma32(bf16x8 a, bf16x8 b, f32x16 c) {
    return __builtin_amdgcn_mfma_f32_32x32x16_bf16(a, b, c, 0, 0, 0);
}

// ---------------- workspace image layout (ushorts) ----------------
// W: [h][c] chunk = 32 opt x 128 k bf16, hi(4096)+lo(4096), row-swizzled col^((opt&15)<<3)
// C: [h][c] chunk = C^T 128 a x 32 opt bf16, swizzled opt^(((a>>1)&3)<<3)
#define WCH    8192
#define CCH    4096
#define WS_C0  (NHEADS * NCH * WCH)                              // 4 MB worth
#define WS_TOTAL_BYTES ((size_t)(WS_C0 + NHEADS * NCH * CCH) * 2) // 6 MB

// ============ prep: f32 -> pre-swizzled bf16 chunk images ============
__global__ __launch_bounds__(256) void vq_prep(const float* __restrict__ W,
                                               const float* __restrict__ C,
                                               unsigned short* __restrict__ ws)
{
    const int b = blockIdx.x, t = threadIdx.x;
    if (b < NHEADS * NCH) {                 // W chunk, hi/lo split
        const float* src = W + (size_t)b * OC * HS;
        unsigned short* dh = ws + (size_t)b * WCH;
        unsigned short* dl = dh + 4096;
        for (int k = 0; k < 16; ++k) {
            const int e = k * 256 + t;      // 4096 elems
            const int opt = e >> 7, col = e & 127;
            const float v = src[e];
            const unsigned short hb = f2bf(v);
            const int idx = opt * 128 + (col ^ ((opt & 15) << 3));
            dh[idx] = hb;
            dl[idx] = f2bf(v - bf2f(hb));
        }
    } else {                                // C chunk -> C^T[a][opt]
        const int b2 = b - NHEADS * NCH;
        const float* src = C + (size_t)b2 * OC * HS;
        unsigned short* dst = ws + WS_C0 + (size_t)b2 * CCH;
        for (int k = 0; k < 16; ++k) {
            const int e = k * 256 + t;
            const int opt = e >> 7, a = e & 127;
            dst[a * 32 + (opt ^ (((a >> 1) & 3) << 3))] = f2bf(src[e]);
        }
    }
}

// ============ main: swapped-QK 32x32 MFMA, online softmax, in-reg P ============
// launch_bounds(256,3): cap VGPR+AGPR at ~168 so 3 blocks/CU are register-feasible
// (R4 was 112 VGPR + 64 AGPR = 176 -> floor(512/176) = 2 waves/SIMD, occupancy 21%).
__global__ __launch_bounds__(256, 3) void vq_main(
    const float* __restrict__ x, const unsigned short* __restrict__ ws,
    const float* __restrict__ temp, float* __restrict__ out)
{
    __shared__ unsigned short wbuf[2][WCH];   // 32 KB (dbuf W hi+lo chunk)
    __shared__ unsigned short cbuf[2][CCH];   // 16 KB (dbuf C^T chunk)

    const int t = threadIdx.x, l = t & 63, w = t >> 6;
    const int la = l & 31, hf = l >> 5;
    const int b = blockIdx.x;
    const int head = ((b & 7) << 1) | ((b >> 3) & 1);   // 2 heads per XCD
    const int n0 = (b >> 4) * TB;

    // ---- DMA chunk 0 (flies under x-prologue) ----
    {
        const char* gw = (const char*)(ws + (size_t)(head * NCH) * WCH) + w * 4096 + l * 16;
        char* lw = (char*)&wbuf[0][0] + w * 4096;
        #pragma unroll
        for (int i = 0; i < 4; ++i) gll16(gw + i * 1024, lw + i * 1024);
        const char* gc = (const char*)(ws + WS_C0 + (size_t)(head * NCH) * CCH) + w * 2048 + l * 16;
        char* lc = (char*)&cbuf[0][0] + w * 2048;
        #pragma unroll
        for (int i = 0; i < 2; ++i) gll16(gc + i * 1024, lc + i * 1024);
    }

    // ---- x row as B-fragments, scaled by invT*log2e, hi/lo split (64 VGPR) ----
    const float sc = (1.0f / temp[0]) * LOG2E;
    bf16x8 xhi[8], xlo[8];
    {
        const float* xr = x + (size_t)(n0 + w * 32 + la) * EMB + head * HS + hf * 8;
        #pragma unroll
        for (int kb = 0; kb < 8; ++kb) {
            const float4 v0 = *(const float4*)(xr + kb * 16);
            const float4 v1 = *(const float4*)(xr + kb * 16 + 4);
            const float vv[8] = {v0.x, v0.y, v0.z, v0.w, v1.x, v1.y, v1.z, v1.w};
            u16x8 hh, ll;
            #pragma unroll
            for (int j = 0; j < 8; ++j) {
                const float f = vv[j] * sc;
                const unsigned short hb = f2bf(f);
                hh[j] = hb;
                ll[j] = f2bf(f - bf2f(hb));
            }
            xhi[kb] = (bf16x8)hh;
            xlo[kb] = (bf16x8)ll;
        }
    }

    f32x16 O0 = (f32x16)0.0f, O1 = (f32x16)0.0f, O2 = (f32x16)0.0f, O3 = (f32x16)0.0f;
    float M = -1.0e30f, sacc = 0.0f;

    __syncthreads();   // drains chunk-0 DMA

    for (int c = 0; c < NCH; ++c) {
        const int cur = c & 1;
        if (c + 1 < NCH) {   // prefetch next chunk (whole chunk of compute to cover it)
            const char* gw = (const char*)(ws + (size_t)(head * NCH + c + 1) * WCH) + w * 4096 + l * 16;
            char* lw = (char*)&wbuf[cur ^ 1][0] + w * 4096;
            #pragma unroll
            for (int i = 0; i < 4; ++i) gll16(gw + i * 1024, lw + i * 1024);
            const char* gc = (const char*)(ws + WS_C0 + (size_t)(head * NCH + c + 1) * CCH) + w * 2048 + l * 16;
            char* lc = (char*)&cbuf[cur ^ 1][0] + w * 2048;
            #pragma unroll
            for (int i = 0; i < 2; ++i) gll16(gc + i * 1024, lc + i * 1024);
        }

        // ---- QK^T swapped: S^T[opt][tok] = W · x^T; A=W (LDS), B=x (regs) ----
        f32x16 sa = (f32x16)0.0f, sb = (f32x16)0.0f;   // 2 chains for MFMA ILP
        const unsigned short* wb = &wbuf[cur][0];
        __builtin_amdgcn_s_setprio(1);
        #pragma unroll
        for (int kb = 0; kb < 8; ++kb) {
            const int idx = la * 128 + ((kb * 16 + hf * 8) ^ ((la & 15) << 3));
            const bf16x8 whi = *(const bf16x8*)&wb[idx];
            const bf16x8 wlo = *(const bf16x8*)&wb[idx + 4096];
            if (kb & 1) {
                sb = mfma32(whi, xhi[kb], sb);
                sb = mfma32(whi, xlo[kb], sb);
                sb = mfma32(wlo, xhi[kb], sb);
            } else {
                sa = mfma32(whi, xhi[kb], sa);
                sa = mfma32(whi, xlo[kb], sa);
                sa = mfma32(wlo, xhi[kb], sa);
            }
        }
        __builtin_amdgcn_s_setprio(0);
        const f32x16 S = sa + sb;   // S in log2 units (invT*log2e folded into x)

        // ---- online softmax (per token = per lane pair) ---- tree-shaped reductions
        float m8[8];
        #pragma unroll
        for (int i = 0; i < 8; ++i) m8[i] = fmaxf(S[2 * i], S[2 * i + 1]);
        float m4a = fmaxf(m8[0], m8[1]), m4b = fmaxf(m8[2], m8[3]);
        float m4c = fmaxf(m8[4], m8[5]), m4d = fmaxf(m8[6], m8[7]);
        float cmax = fmaxf(fmaxf(m4a, m4b), fmaxf(m4c, m4d));
        cmax = fmaxf(cmax, __shfl_xor(cmax, 32));
        if (__any(cmax > M + THRD)) {          // rare rescale (defer-max, T13)
            const float Mn = fmaxf(M, cmax);
            const float fr = exp2f(M - Mn);    // first chunk: exp2(-1e30)=0
            M = Mn;
            sacc *= fr;
            #pragma unroll
            for (int q = 0; q < 16; ++q) {
                const int row = (q & 3) + 8 * (q >> 2) + 4 * hf;
                const float f = __shfl(fr, row);
                O0[q] *= f; O1[q] *= f; O2[q] *= f; O3[q] *= f;
            }
        }
        float pv[16];
        #pragma unroll
        for (int q = 0; q < 16; ++q) pv[q] = exp2f(S[q] - M);
        {   // tree sum
            float s8[8];
            #pragma unroll
            for (int i = 0; i < 8; ++i) s8[i] = pv[2 * i] + pv[2 * i + 1];
            const float s4a = s8[0] + s8[1], s4b = s8[2] + s8[3];
            const float s4c = s8[4] + s8[5], s4d = s8[6] + s8[7];
            sacc += (s4a + s4b) + (s4c + s4d);
        }

        // ---- P -> bf16 A-fragments fully in-register (T12) ----
        unsigned pk0 = cvtpk(pv[0],  pv[1]),  pk1 = cvtpk(pv[2],  pv[3]);
        unsigned pk2 = cvtpk(pv[4],  pv[5]),  pk3 = cvtpk(pv[6],  pv[7]);
        unsigned pk4 = cvtpk(pv[8],  pv[9]),  pk5 = cvtpk(pv[10], pv[11]);
        unsigned pk6 = cvtpk(pv[12], pv[13]), pk7 = cvtpk(pv[14], pv[15]);
        pl32swap(pk0, pk2);
        pl32swap(pk1, pk3);
        pl32swap(pk4, pk6);
        pl32swap(pk5, pk7);
        const bf16x8 pa0 = __builtin_bit_cast(bf16x8, (u32x4){pk0, pk1, pk2, pk3});
        const bf16x8 pa1 = __builtin_bit_cast(bf16x8, (u32x4){pk4, pk5, pk6, pk7});

        // ---- PV: O += P · C  (A=P regs, B=C^T LDS) ----
        const unsigned short* cb = &cbuf[cur][0];
        __builtin_amdgcn_s_setprio(1);
        {
            const int a0 = la;
            const int sw0 = ((a0 >> 1) & 3) << 3;
            O0 = mfma32(pa0, *(const bf16x8*)&cb[a0 * 32 + ((hf * 8) ^ sw0)], O0);
            O0 = mfma32(pa1, *(const bf16x8*)&cb[a0 * 32 + ((16 + hf * 8) ^ sw0)], O0);
            const int a1 = 32 + la;
            const int sw1 = ((a1 >> 1) & 3) << 3;
            O1 = mfma32(pa0, *(const bf16x8*)&cb[a1 * 32 + ((hf * 8) ^ sw1)], O1);
            O1 = mfma32(pa1, *(const bf16x8*)&cb[a1 * 32 + ((16 + hf * 8) ^ sw1)], O1);
            const int a2 = 64 + la;
            const int sw2 = ((a2 >> 1) & 3) << 3;
            O2 = mfma32(pa0, *(const bf16x8*)&cb[a2 * 32 + ((hf * 8) ^ sw2)], O2);
            O2 = mfma32(pa1, *(const bf16x8*)&cb[a2 * 32 + ((16 + hf * 8) ^ sw2)], O2);
            const int a3 = 96 + la;
            const int sw3 = ((a3 >> 1) & 3) << 3;
            O3 = mfma32(pa0, *(const bf16x8*)&cb[a3 * 32 + ((hf * 8) ^ sw3)], O3);
            O3 = mfma32(pa1, *(const bf16x8*)&cb[a3 * 32 + ((16 + hf * 8) ^ sw3)], O3);
        }
        __builtin_amdgcn_s_setprio(0);
        __syncthreads();   // drains next-chunk DMA; separates buffer reuse
    }

    // ---- epilogue: normalize by 1/sum, coalesced stores ----
    const float stot = sacc + __shfl_xor(sacc, 32);
    const float rs = 1.0f / stot;
    #pragma unroll
    for (int q = 0; q < 16; ++q) {
        const int row = (q & 3) + 8 * (q >> 2) + 4 * hf;
        const float rq = __shfl(rs, row);
        float* op = out + (size_t)(n0 + w * 32 + row) * EMB + head * HS + la;
        op[0]  = O0[q] * rq;
        op[32] = O1[q] * rq;
        op[64] = O2[q] * rq;
        op[96] = O3[q] * rq;
    }
}

// ============ fallback (Round-2 kernel, no workspace needed) ============
__global__ __launch_bounds__(256, 2) void vq_fwd_mfma(
    const float* __restrict__ x, const float* __restrict__ W,
    const float* __restrict__ C, const float* __restrict__ temp,
    float* __restrict__ out)
{
    __shared__ unsigned short xh_lds[64 * HS];
    __shared__ unsigned short xl_lds[64 * HS];
    __shared__ unsigned short wst[2][64 * HS];
    __shared__ unsigned short p_lds[4][16 * 64];

    const int t = threadIdx.x, l = t & 63, w = t >> 6, lr = l & 15, lk = l >> 4;
    const int b = blockIdx.x;
    const int h = ((b & 7) << 1) | ((b >> 3) & 1);
    const int n0 = (b >> 4) * 64;
    const float invT = 1.0f / temp[0];

    #pragma unroll
    for (int kk = 0; kk < 4; ++kk) {
        const int g = t + 256 * kk;
        const int row = g >> 4, c8 = (g & 15) * 8;
        const float* src = x + (size_t)(n0 + row) * EMB + h * HS + c8;
        const float4 v0 = *(const float4*)src;
        const float4 v1 = *(const float4*)(src + 4);
        float vv[8] = {v0.x, v0.y, v0.z, v0.w, v1.x, v1.y, v1.z, v1.w};
        u16x8 hh, ll;
        #pragma unroll
        for (int j = 0; j < 8; ++j) {
            const unsigned short hb = f2bf(vv[j]);
            hh[j] = hb; ll[j] = f2bf(vv[j] - bf2f(hb));
        }
        const int idx = row * HS + (c8 ^ ((row & 7) << 3));
        *(u16x8*)&xh_lds[idx] = hh;
        *(u16x8*)&xl_lds[idx] = ll;
    }

    f32x4 acc[32];
    #pragma unroll
    for (int i = 0; i < 32; ++i) acc[i] = f32x4{0.f, 0.f, 0.f, 0.f};
    bf16x8 axh[4], axl[4];

    #pragma unroll
    for (int c = 0; c < 8; ++c) {
        if (c) __syncthreads();
        #pragma unroll
        for (int kk = 0; kk < 4; ++kk) {
            const int g = t + 256 * kk;
            const int row = g >> 4, c8 = (g & 15) * 8;
            const float* src = W + ((size_t)h * NOPT + c * 64 + row) * HS + c8;
            const float4 v0 = *(const float4*)src;
            const float4 v1 = *(const float4*)(src + 4);
            float vv[8] = {v0.x, v0.y, v0.z, v0.w, v1.x, v1.y, v1.z, v1.w};
            u16x8 hh, ll;
            #pragma unroll
            for (int j = 0; j < 8; ++j) {
                const unsigned short hb = f2bf(vv[j]);
                hh[j] = hb; ll[j] = f2bf(vv[j] - bf2f(hb));
            }
            const int idx = row * HS + (c8 ^ ((row & 7) << 3));
            *(u16x8*)&wst[0][idx] = hh;
            *(u16x8*)&wst[1][idx] = ll;
        }
        __syncthreads();
        if (c == 0) {
            const int arow = w * 16 + lr;
            #pragma unroll
            for (int ks = 0; ks < 4; ++ks) {
                const int ai = arow * HS + ((lk * 8 + ks * 32) ^ ((arow & 7) << 3));
                axh[ks] = *(const bf16x8*)&xh_lds[ai];
                axl[ks] = *(const bf16x8*)&xl_lds[ai];
            }
        }
        #pragma unroll
        for (int nt = 0; nt < 4; ++nt) {
            const int brow = nt * 16 + lr;
            #pragma unroll
            for (int ks = 0; ks < 4; ++ks) {
                const int bi = brow * HS + ((lk * 8 + ks * 32) ^ ((brow & 7) << 3));
                const bf16x8 bh = *(const bf16x8*)&wst[0][bi];
                const bf16x8 bl = *(const bf16x8*)&wst[1][bi];
                acc[c*4+nt] = __builtin_amdgcn_mfma_f32_16x16x32_bf16(axh[ks], bh, acc[c*4+nt], 0, 0, 0);
                acc[c*4+nt] = __builtin_amdgcn_mfma_f32_16x16x32_bf16(axl[ks], bh, acc[c*4+nt], 0, 0, 0);
                acc[c*4+nt] = __builtin_amdgcn_mfma_f32_16x16x32_bf16(axh[ks], bl, acc[c*4+nt], 0, 0, 0);
            }
        }
    }

    float mx[4], rsn[4];
    #pragma unroll
    for (int r = 0; r < 4; ++r) {
        float m = -3.0e38f;
        #pragma unroll
        for (int i = 0; i < 32; ++i) m = fmaxf(m, acc[i][r]);
        m *= invT;
        #pragma unroll
        for (int s = 1; s < 16; s <<= 1) m = fmaxf(m, __shfl_xor(m, s));
        float sum = 0.f;
        #pragma unroll
        for (int i = 0; i < 32; ++i) sum += exp2f((acc[i][r] * invT - m) * LOG2E);
        #pragma unroll
        for (int s = 1; s < 16; s <<= 1) sum += __shfl_xor(sum, s);
        mx[r] = m; rsn[r] = 1.0f / sum;
    }

    f32x4 oacc[8];
    #pragma unroll
    for (int i = 0; i < 8; ++i) oacc[i] = f32x4{0.f, 0.f, 0.f, 0.f};
    const int pr_ = t & 31, ag = t >> 5;
    #pragma unroll
    for (int c = 0; c < 8; ++c) {
        __syncthreads();
        {
            const float* c0p = C + ((size_t)h * NOPT + c * 64 + 2 * pr_) * HS + ag * 16;
            float va[16], vb[16];
            #pragma unroll
            for (int q = 0; q < 4; ++q) {
                const float4 u0 = ((const float4*)c0p)[q];
                const float4 u1 = ((const float4*)(c0p + HS))[q];
                va[q*4+0] = u0.x; va[q*4+1] = u0.y; va[q*4+2] = u0.z; va[q*4+3] = u0.w;
                vb[q*4+0] = u1.x; vb[q*4+1] = u1.y; vb[q*4+2] = u1.z; vb[q*4+3] = u1.w;
            }
            unsigned* ct32 = (unsigned*)&wst[0][0];
            #pragma unroll
            for (int j = 0; j < 16; ++j) {
                const int a = ag * 16 + j;
                const unsigned pkv = (unsigned)f2bf(va[j]) | ((unsigned)f2bf(vb[j]) << 16);
                ct32[a * 32 + (pr_ ^ ((a & 7) << 2))] = pkv;
            }
        }
        #pragma unroll
        for (int nt = 0; nt < 4; ++nt) {
            #pragma unroll
            for (int r = 0; r < 4; ++r) {
                const float p = exp2f((acc[c*4+nt][r] * invT - mx[r]) * LOG2E);
                const int prow = lk * 4 + r;
                const int pcol = nt * 16 + lr;
                p_lds[w][prow * 64 + (pcol ^ ((prow & 7) << 3))] = f2bf(p);
            }
        }
        __syncthreads();
        #pragma unroll
        for (int ks = 0; ks < 2; ++ks) {
            const int ai = lr * 64 + ((lk * 8 + ks * 32) ^ ((lr & 7) << 3));
            const bf16x8 pa = *(const bf16x8*)&p_lds[w][ai];
            #pragma unroll
            for (int nt = 0; nt < 8; ++nt) {
                const int brow = nt * 16 + lr;
                const int bi = brow * 64 + ((lk * 8 + ks * 32) ^ ((brow & 7) << 3));
                const bf16x8 cbv = *(const bf16x8*)&wst[0][bi];
                oacc[nt] = __builtin_amdgcn_mfma_f32_16x16x32_bf16(pa, cbv, oacc[nt], 0, 0, 0);
            }
        }
    }

    #pragma unroll
    for (int nt = 0; nt < 8; ++nt) {
        #pragma unroll
        for (int r = 0; r < 4; ++r) {
            const int tok = n0 + w * 16 + lk * 4 + r;
            out[(size_t)tok * EMB + h * HS + nt * 16 + lr] = oacc[nt][r] * rsn[r];
        }
    }
}

extern "C" void kernel_launch(void* const* d_in, const int* in_sizes, int n_in,
                              void* d_out, int out_size, void* d_ws, size_t ws_size,
                              hipStream_t stream) {
    const float* x = (const float*)d_in[0];
    const float* W = (const float*)d_in[1];
    const float* C = (const float*)d_in[2];
    const float* T = (const float*)d_in[3];
    float* out     = (float*)d_out;

    const int ntok = in_sizes[0] / EMB;   // 8192

    if (ws_size >= WS_TOTAL_BYTES) {
        hipLaunchKernelGGL(vq_prep, dim3(NHEADS * NCH * 2), dim3(256), 0, stream,
                           W, C, (unsigned short*)d_ws);
        const int nblk = (ntok / TB) * NHEADS;   // 1024
        hipLaunchKernelGGL(vq_main, dim3(nblk), dim3(256), 0, stream,
                           x, (const unsigned short*)d_ws, T, out);
    } else {
        const int nblk = (ntok / 64) * NHEADS;   // 2048
        hipLaunchKernelGGL(vq_fwd_mfma, dim3(nblk), dim3(256), 0, stream,
                           x, W, C, T, out);
    }
}

// Round 7
// 98.649 us; speedup vs baseline: 2.1543x; 2.1543x over previous
//
#include <hip/hip_runtime.h>
#include <math.h>

#define NHEADS 16
#define HS     128
#define NOPT   512
#define TB     128      // tokens per block (4 waves x 32)
#define OC     32       // options per chunk
#define NCH    16       // chunks
#define EMB    2048
#define LOG2E  1.44269504088896340736f
#define THRD   11.0f    // defer-max threshold (log2 units): P <= 2^11, f32 sum safe

typedef short bf16x8 __attribute__((ext_vector_type(8)));
typedef unsigned short u16x8 __attribute__((ext_vector_type(8)));
typedef float f32x4 __attribute__((ext_vector_type(4)));
typedef float f32x16 __attribute__((ext_vector_type(16)));
typedef unsigned u32x4 __attribute__((ext_vector_type(4)));

__device__ __forceinline__ unsigned short f2bf(float f) {
    union { float f; unsigned u; } v; v.f = f;
    unsigned r = v.u + 0x7FFFu + ((v.u >> 16) & 1u);   // rn-even
    return (unsigned short)(r >> 16);
}
__device__ __forceinline__ float bf2f(unsigned short h) {
    union { unsigned u; float f; } v; v.u = ((unsigned)h) << 16;
    return v.f;
}
__device__ __forceinline__ void gll16(const void* gptr, void* lptr) {
    __builtin_amdgcn_global_load_lds(
        (const __attribute__((address_space(1))) void*)gptr,
        (__attribute__((address_space(3))) void*)lptr,
        16, 0, 0);
}
__device__ __forceinline__ unsigned cvtpk(float lo, float hi) {
    unsigned r;
    asm("v_cvt_pk_bf16_f32 %0, %1, %2" : "=v"(r) : "v"(lo), "v"(hi));
    return r;
}
// v_permlane32_swap_b32: a' = {a.lo, b.lo_old}, b' = {a.hi_old, b.hi}
__device__ __forceinline__ void pl32swap(unsigned &a, unsigned &b) {
    asm volatile("v_permlane32_swap_b32 %0, %1" : "+v"(a), "+v"(b));
}
__device__ __forceinline__ f32x16 mfma32(bf16x8 a, bf16x8 b, f32x16 c) {
    return __builtin_amdgcn_mfma_f32_32x32x16_bf16(a, b, c, 0, 0, 0);
}

// ---------------- workspace image layout (ushorts) ----------------
// W: [h][c] chunk = 32 opt x 128 k bf16, hi(4096)+lo(4096), row-swizzled col^((opt&15)<<3)
// C: [h][c] chunk = C^T 128 a x 32 opt bf16, swizzled opt^(((a>>1)&3)<<3)
#define WCH    8192
#define CCH    4096
#define WS_C0  (NHEADS * NCH * WCH)                              // 4 MB worth
#define WS_TOTAL_BYTES ((size_t)(WS_C0 + NHEADS * NCH * CCH) * 2) // 6 MB

// ============ prep: f32 -> pre-swizzled bf16 chunk images ============
__global__ __launch_bounds__(256) void vq_prep(const float* __restrict__ W,
                                               const float* __restrict__ C,
                                               unsigned short* __restrict__ ws)
{
    const int b = blockIdx.x, t = threadIdx.x;
    if (b < NHEADS * NCH) {                 // W chunk, hi/lo split
        const float* src = W + (size_t)b * OC * HS;
        unsigned short* dh = ws + (size_t)b * WCH;
        unsigned short* dl = dh + 4096;
        for (int k = 0; k < 16; ++k) {
            const int e = k * 256 + t;      // 4096 elems
            const int opt = e >> 7, col = e & 127;
            const float v = src[e];
            const unsigned short hb = f2bf(v);
            const int idx = opt * 128 + (col ^ ((opt & 15) << 3));
            dh[idx] = hb;
            dl[idx] = f2bf(v - bf2f(hb));
        }
    } else {                                // C chunk -> C^T[a][opt]
        const int b2 = b - NHEADS * NCH;
        const float* src = C + (size_t)b2 * OC * HS;
        unsigned short* dst = ws + WS_C0 + (size_t)b2 * CCH;
        for (int k = 0; k < 16; ++k) {
            const int e = k * 256 + t;
            const int opt = e >> 7, a = e & 127;
            dst[a * 32 + (opt ^ (((a >> 1) & 3) << 3))] = f2bf(src[e]);
        }
    }
}

// QK^T for one chunk: S^T[opt][tok] = W(hi+lo) · x(hi/lo)^T, 3-product split.
// Numerics identical to R4 (passed at absmax 0.03125).
__device__ __forceinline__ f32x16 qk_chunk(const unsigned short* __restrict__ wb,
                                           const bf16x8* xhi, const bf16x8* xlo,
                                           int la, int hf)
{
    f32x16 sa = (f32x16)0.0f, sb = (f32x16)0.0f;   // 2 chains for MFMA ILP
    #pragma unroll
    for (int kb = 0; kb < 8; ++kb) {
        const int idx = la * 128 + ((kb * 16 + hf * 8) ^ ((la & 15) << 3));
        const bf16x8 whi = *(const bf16x8*)&wb[idx];
        const bf16x8 wlo = *(const bf16x8*)&wb[idx + 4096];
        if (kb & 1) {
            sb = mfma32(whi, xhi[kb], sb);
            sb = mfma32(whi, xlo[kb], sb);
            sb = mfma32(wlo, xhi[kb], sb);
        } else {
            sa = mfma32(whi, xhi[kb], sa);
            sa = mfma32(whi, xlo[kb], sa);
            sa = mfma32(wlo, xhi[kb], sa);
        }
    }
    return sa + sb;
}

// ============ main: swapped-QK 32x32 MFMA, online softmax, in-reg P ============
// R7: software-pipelined — QK(c+1) issued BEFORE softmax(c)+PV(c) so the
// scheduler interleaves softmax VALU into the QK MFMA shadow. S carried one
// iteration (+16 VGPR, ~192 total: still 2 waves/SIMD, far from spill).
__global__ __launch_bounds__(256, 2) void vq_main(
    const float* __restrict__ x, const unsigned short* __restrict__ ws,
    const float* __restrict__ temp, float* __restrict__ out)
{
    __shared__ unsigned short wbuf[2][WCH];   // 32 KB (dbuf W hi+lo chunk)
    __shared__ unsigned short cbuf[2][CCH];   // 16 KB (dbuf C^T chunk)

    const int t = threadIdx.x, l = t & 63, w = t >> 6;
    const int la = l & 31, hf = l >> 5;
    const int b = blockIdx.x;
    const int head = ((b & 7) << 1) | ((b >> 3) & 1);   // 2 heads per XCD
    const int n0 = (b >> 4) * TB;

    // ---- prologue DMA: W(0)->wbuf[0], W(1)->wbuf[1], C(0)->cbuf[0] ----
    {
        const char* gw0 = (const char*)(ws + (size_t)(head * NCH) * WCH) + w * 4096 + l * 16;
        char* lw0 = (char*)&wbuf[0][0] + w * 4096;
        #pragma unroll
        for (int i = 0; i < 4; ++i) gll16(gw0 + i * 1024, lw0 + i * 1024);
        const char* gw1 = (const char*)(ws + (size_t)(head * NCH + 1) * WCH) + w * 4096 + l * 16;
        char* lw1 = (char*)&wbuf[1][0] + w * 4096;
        #pragma unroll
        for (int i = 0; i < 4; ++i) gll16(gw1 + i * 1024, lw1 + i * 1024);
        const char* gc = (const char*)(ws + WS_C0 + (size_t)(head * NCH) * CCH) + w * 2048 + l * 16;
        char* lc = (char*)&cbuf[0][0] + w * 2048;
        #pragma unroll
        for (int i = 0; i < 2; ++i) gll16(gc + i * 1024, lc + i * 1024);
    }

    // ---- x row as B-fragments, scaled by invT*log2e, hi/lo split (64 VGPR) ----
    const float sc = (1.0f / temp[0]) * LOG2E;
    bf16x8 xhi[8], xlo[8];
    {
        const float* xr = x + (size_t)(n0 + w * 32 + la) * EMB + head * HS + hf * 8;
        #pragma unroll
        for (int kb = 0; kb < 8; ++kb) {
            const float4 v0 = *(const float4*)(xr + kb * 16);
            const float4 v1 = *(const float4*)(xr + kb * 16 + 4);
            const float vv[8] = {v0.x, v0.y, v0.z, v0.w, v1.x, v1.y, v1.z, v1.w};
            u16x8 hh, ll;
            #pragma unroll
            for (int j = 0; j < 8; ++j) {
                const float f = vv[j] * sc;
                const unsigned short hb = f2bf(f);
                hh[j] = hb;
                ll[j] = f2bf(f - bf2f(hb));
            }
            xhi[kb] = (bf16x8)hh;
            xlo[kb] = (bf16x8)ll;
        }
    }

    f32x16 O0 = (f32x16)0.0f, O1 = (f32x16)0.0f, O2 = (f32x16)0.0f, O3 = (f32x16)0.0f;
    float M = -1.0e30f, sacc = 0.0f;

    __syncthreads();   // drains W0, W1, C0

    // ---- pipeline prime: S(0); extra barrier so iter-0's W(2) DMA cannot
    //      overwrite wbuf[0] while a lagging wave still reads it ----
    f32x16 Scur = qk_chunk(&wbuf[0][0], xhi, xlo, la, hf);
    __syncthreads();

    for (int c = 0; c < NCH; ++c) {
        const int cur = c & 1;
        // DMA: W(c+2) -> wbuf[cur] (last read: QK(c) in iter c-1, pre-barrier);
        //      C(c+1) -> cbuf[cur^1] (last read: PV(c-1) in iter c-1, pre-barrier).
        if (c + 2 < NCH) {
            const char* gw = (const char*)(ws + (size_t)(head * NCH + c + 2) * WCH) + w * 4096 + l * 16;
            char* lw = (char*)&wbuf[cur][0] + w * 4096;
            #pragma unroll
            for (int i = 0; i < 4; ++i) gll16(gw + i * 1024, lw + i * 1024);
        }
        if (c + 1 < NCH) {
            const char* gc = (const char*)(ws + WS_C0 + (size_t)(head * NCH + c + 1) * CCH) + w * 2048 + l * 16;
            char* lc = (char*)&cbuf[cur ^ 1][0] + w * 2048;
            #pragma unroll
            for (int i = 0; i < 2; ++i) gll16(gc + i * 1024, lc + i * 1024);
        }

        // ---- QK(c+1): independent of softmax(c)/PV(c); its MFMA shadow hides
        //      the softmax VALU chain below ----
        f32x16 Snext = Scur;
        if (c + 1 < NCH) Snext = qk_chunk(&wbuf[cur ^ 1][0], xhi, xlo, la, hf);

        // ---- online softmax on S(c) (per token = per lane), tree reductions ----
        const f32x16 S = Scur;
        float m8[8];
        #pragma unroll
        for (int i = 0; i < 8; ++i) m8[i] = fmaxf(S[2 * i], S[2 * i + 1]);
        float m4a = fmaxf(m8[0], m8[1]), m4b = fmaxf(m8[2], m8[3]);
        float m4c = fmaxf(m8[4], m8[5]), m4d = fmaxf(m8[6], m8[7]);
        float cmax = fmaxf(fmaxf(m4a, m4b), fmaxf(m4c, m4d));
        cmax = fmaxf(cmax, __shfl_xor(cmax, 32));
        if (__any(cmax > M + THRD)) {          // rare rescale (defer-max, T13)
            const float Mn = fmaxf(M, cmax);
            const float fr = exp2f(M - Mn);    // first chunk: exp2(-1e30)=0
            M = Mn;
            sacc *= fr;
            #pragma unroll
            for (int q = 0; q < 16; ++q) {
                const int row = (q & 3) + 8 * (q >> 2) + 4 * hf;
                const float f = __shfl(fr, row);
                O0[q] *= f; O1[q] *= f; O2[q] *= f; O3[q] *= f;
            }
        }
        float pv[16];
        #pragma unroll
        for (int q = 0; q < 16; ++q) pv[q] = exp2f(S[q] - M);
        {   // tree sum
            float s8[8];
            #pragma unroll
            for (int i = 0; i < 8; ++i) s8[i] = pv[2 * i] + pv[2 * i + 1];
            const float s4a = s8[0] + s8[1], s4b = s8[2] + s8[3];
            const float s4c = s8[4] + s8[5], s4d = s8[6] + s8[7];
            sacc += (s4a + s4b) + (s4c + s4d);
        }

        // ---- P -> bf16 A-fragments fully in-register (T12) ----
        unsigned pk0 = cvtpk(pv[0],  pv[1]),  pk1 = cvtpk(pv[2],  pv[3]);
        unsigned pk2 = cvtpk(pv[4],  pv[5]),  pk3 = cvtpk(pv[6],  pv[7]);
        unsigned pk4 = cvtpk(pv[8],  pv[9]),  pk5 = cvtpk(pv[10], pv[11]);
        unsigned pk6 = cvtpk(pv[12], pv[13]), pk7 = cvtpk(pv[14], pv[15]);
        pl32swap(pk0, pk2);
        pl32swap(pk1, pk3);
        pl32swap(pk4, pk6);
        pl32swap(pk5, pk7);
        const bf16x8 pa0 = __builtin_bit_cast(bf16x8, (u32x4){pk0, pk1, pk2, pk3});
        const bf16x8 pa1 = __builtin_bit_cast(bf16x8, (u32x4){pk4, pk5, pk6, pk7});

        // ---- PV: O += P · C  (A=P regs, B=C^T LDS) ----
        const unsigned short* cb = &cbuf[cur][0];
        {
            const int a0 = la;
            const int sw0 = ((a0 >> 1) & 3) << 3;
            O0 = mfma32(pa0, *(const bf16x8*)&cb[a0 * 32 + ((hf * 8) ^ sw0)], O0);
            O0 = mfma32(pa1, *(const bf16x8*)&cb[a0 * 32 + ((16 + hf * 8) ^ sw0)], O0);
            const int a1 = 32 + la;
            const int sw1 = ((a1 >> 1) & 3) << 3;
            O1 = mfma32(pa0, *(const bf16x8*)&cb[a1 * 32 + ((hf * 8) ^ sw1)], O1);
            O1 = mfma32(pa1, *(const bf16x8*)&cb[a1 * 32 + ((16 + hf * 8) ^ sw1)], O1);
            const int a2 = 64 + la;
            const int sw2 = ((a2 >> 1) & 3) << 3;
            O2 = mfma32(pa0, *(const bf16x8*)&cb[a2 * 32 + ((hf * 8) ^ sw2)], O2);
            O2 = mfma32(pa1, *(const bf16x8*)&cb[a2 * 32 + ((16 + hf * 8) ^ sw2)], O2);
            const int a3 = 96 + la;
            const int sw3 = ((a3 >> 1) & 3) << 3;
            O3 = mfma32(pa0, *(const bf16x8*)&cb[a3 * 32 + ((hf * 8) ^ sw3)], O3);
            O3 = mfma32(pa1, *(const bf16x8*)&cb[a3 * 32 + ((16 + hf * 8) ^ sw3)], O3);
        }
        __syncthreads();   // drains this iter's DMA; separates buffer reuse
        Scur = Snext;
    }

    // ---- epilogue: normalize by 1/sum, coalesced stores ----
    const float stot = sacc + __shfl_xor(sacc, 32);
    const float rs = 1.0f / stot;
    #pragma unroll
    for (int q = 0; q < 16; ++q) {
        const int row = (q & 3) + 8 * (q >> 2) + 4 * hf;
        const float rq = __shfl(rs, row);
        float* op = out + (size_t)(n0 + w * 32 + row) * EMB + head * HS + la;
        op[0]  = O0[q] * rq;
        op[32] = O1[q] * rq;
        op[64] = O2[q] * rq;
        op[96] = O3[q] * rq;
    }
}

// ============ fallback (Round-2 kernel, no workspace needed) ============
__global__ __launch_bounds__(256, 2) void vq_fwd_mfma(
    const float* __restrict__ x, const float* __restrict__ W,
    const float* __restrict__ C, const float* __restrict__ temp,
    float* __restrict__ out)
{
    __shared__ unsigned short xh_lds[64 * HS];
    __shared__ unsigned short xl_lds[64 * HS];
    __shared__ unsigned short wst[2][64 * HS];
    __shared__ unsigned short p_lds[4][16 * 64];

    const int t = threadIdx.x, l = t & 63, w = t >> 6, lr = l & 15, lk = l >> 4;
    const int b = blockIdx.x;
    const int h = ((b & 7) << 1) | ((b >> 3) & 1);
    const int n0 = (b >> 4) * 64;
    const float invT = 1.0f / temp[0];

    #pragma unroll
    for (int kk = 0; kk < 4; ++kk) {
        const int g = t + 256 * kk;
        const int row = g >> 4, c8 = (g & 15) * 8;
        const float* src = x + (size_t)(n0 + row) * EMB + h * HS + c8;
        const float4 v0 = *(const float4*)src;
        const float4 v1 = *(const float4*)(src + 4);
        float vv[8] = {v0.x, v0.y, v0.z, v0.w, v1.x, v1.y, v1.z, v1.w};
        u16x8 hh, ll;
        #pragma unroll
        for (int j = 0; j < 8; ++j) {
            const unsigned short hb = f2bf(vv[j]);
            hh[j] = hb; ll[j] = f2bf(vv[j] - bf2f(hb));
        }
        const int idx = row * HS + (c8 ^ ((row & 7) << 3));
        *(u16x8*)&xh_lds[idx] = hh;
        *(u16x8*)&xl_lds[idx] = ll;
    }

    f32x4 acc[32];
    #pragma unroll
    for (int i = 0; i < 32; ++i) acc[i] = f32x4{0.f, 0.f, 0.f, 0.f};
    bf16x8 axh[4], axl[4];

    #pragma unroll
    for (int c = 0; c < 8; ++c) {
        if (c) __syncthreads();
        #pragma unroll
        for (int kk = 0; kk < 4; ++kk) {
            const int g = t + 256 * kk;
            const int row = g >> 4, c8 = (g & 15) * 8;
            const float* src = W + ((size_t)h * NOPT + c * 64 + row) * HS + c8;
            const float4 v0 = *(const float4*)src;
            const float4 v1 = *(const float4*)(src + 4);
            float vv[8] = {v0.x, v0.y, v0.z, v0.w, v1.x, v1.y, v1.z, v1.w};
            u16x8 hh, ll;
            #pragma unroll
            for (int j = 0; j < 8; ++j) {
                const unsigned short hb = f2bf(vv[j]);
                hh[j] = hb; ll[j] = f2bf(vv[j] - bf2f(hb));
            }
            const int idx = row * HS + (c8 ^ ((row & 7) << 3));
            *(u16x8*)&wst[0][idx] = hh;
            *(u16x8*)&wst[1][idx] = ll;
        }
        __syncthreads();
        if (c == 0) {
            const int arow = w * 16 + lr;
            #pragma unroll
            for (int ks = 0; ks < 4; ++ks) {
                const int ai = arow * HS + ((lk * 8 + ks * 32) ^ ((arow & 7) << 3));
                axh[ks] = *(const bf16x8*)&xh_lds[ai];
                axl[ks] = *(const bf16x8*)&xl_lds[ai];
            }
        }
        #pragma unroll
        for (int nt = 0; nt < 4; ++nt) {
            const int brow = nt * 16 + lr;
            #pragma unroll
            for (int ks = 0; ks < 4; ++ks) {
                const int bi = brow * HS + ((lk * 8 + ks * 32) ^ ((brow & 7) << 3));
                const bf16x8 bh = *(const bf16x8*)&wst[0][bi];
                const bf16x8 bl = *(const bf16x8*)&wst[1][bi];
                acc[c*4+nt] = __builtin_amdgcn_mfma_f32_16x16x32_bf16(axh[ks], bh, acc[c*4+nt], 0, 0, 0);
                acc[c*4+nt] = __builtin_amdgcn_mfma_f32_16x16x32_bf16(axl[ks], bh, acc[c*4+nt], 0, 0, 0);
                acc[c*4+nt] = __builtin_amdgcn_mfma_f32_16x16x32_bf16(axh[ks], bl, acc[c*4+nt], 0, 0, 0);
            }
        }
    }

    float mx[4], rsn[4];
    #pragma unroll
    for (int r = 0; r < 4; ++r) {
        float m = -3.0e38f;
        #pragma unroll
        for (int i = 0; i < 32; ++i) m = fmaxf(m, acc[i][r]);
        m *= invT;
        #pragma unroll
        for (int s = 1; s < 16; s <<= 1) m = fmaxf(m, __shfl_xor(m, s));
        float sum = 0.f;
        #pragma unroll
        for (int i = 0; i < 32; ++i) sum += exp2f((acc[i][r] * invT - m) * LOG2E);
        #pragma unroll
        for (int s = 1; s < 16; s <<= 1) sum += __shfl_xor(sum, s);
        mx[r] = m; rsn[r] = 1.0f / sum;
    }

    f32x4 oacc[8];
    #pragma unroll
    for (int i = 0; i < 8; ++i) oacc[i] = f32x4{0.f, 0.f, 0.f, 0.f};
    const int pr_ = t & 31, ag = t >> 5;
    #pragma unroll
    for (int c = 0; c < 8; ++c) {
        __syncthreads();
        {
            const float* c0p = C + ((size_t)h * NOPT + c * 64 + 2 * pr_) * HS + ag * 16;
            float va[16], vb[16];
            #pragma unroll
            for (int q = 0; q < 4; ++q) {
                const float4 u0 = ((const float4*)c0p)[q];
                const float4 u1 = ((const float4*)(c0p + HS))[q];
                va[q*4+0] = u0.x; va[q*4+1] = u0.y; va[q*4+2] = u0.z; va[q*4+3] = u0.w;
                vb[q*4+0] = u1.x; vb[q*4+1] = u1.y; vb[q*4+2] = u1.z; vb[q*4+3] = u1.w;
            }
            unsigned* ct32 = (unsigned*)&wst[0][0];
            #pragma unroll
            for (int j = 0; j < 16; ++j) {
                const int a = ag * 16 + j;
                const unsigned pkv = (unsigned)f2bf(va[j]) | ((unsigned)f2bf(vb[j]) << 16);
                ct32[a * 32 + (pr_ ^ ((a & 7) << 2))] = pkv;
            }
        }
        #pragma unroll
        for (int nt = 0; nt < 4; ++nt) {
            #pragma unroll
            for (int r = 0; r < 4; ++r) {
                const float p = exp2f((acc[c*4+nt][r] * invT - mx[r]) * LOG2E);
                const int prow = lk * 4 + r;
                const int pcol = nt * 16 + lr;
                p_lds[w][prow * 64 + (pcol ^ ((prow & 7) << 3))] = f2bf(p);
            }
        }
        __syncthreads();
        #pragma unroll
        for (int ks = 0; ks < 2; ++ks) {
            const int ai = lr * 64 + ((lk * 8 + ks * 32) ^ ((lr & 7) << 3));
            const bf16x8 pa = *(const bf16x8*)&p_lds[w][ai];
            #pragma unroll
            for (int nt = 0; nt < 8; ++nt) {
                const int brow = nt * 16 + lr;
                const int bi = brow * 64 + ((lk * 8 + ks * 32) ^ ((brow & 7) << 3));
                const bf16x8 cbv = *(const bf16x8*)&wst[0][bi];
                oacc[nt] = __builtin_amdgcn_mfma_f32_16x16x32_bf16(pa, cbv, oacc[nt], 0, 0, 0);
            }
        }
    }

    #pragma unroll
    for (int nt = 0; nt < 8; ++nt) {
        #pragma unroll
        for (int r = 0; r < 4; ++r) {
            const int tok = n0 + w * 16 + lk * 4 + r;
            out[(size_t)tok * EMB + h * HS + nt * 16 + lr] = oacc[nt][r] * rsn[r];
        }
    }
}

extern "C" void kernel_launch(void* const* d_in, const int* in_sizes, int n_in,
                              void* d_out, int out_size, void* d_ws, size_t ws_size,
                              hipStream_t stream) {
    const float* x = (const float*)d_in[0];
    const float* W = (const float*)d_in[1];
    const float* C = (const float*)d_in[2];
    const float* T = (const float*)d_in[3];
    float* out     = (float*)d_out;

    const int ntok = in_sizes[0] / EMB;   // 8192

    if (ws_size >= WS_TOTAL_BYTES) {
        hipLaunchKernelGGL(vq_prep, dim3(NHEADS * NCH * 2), dim3(256), 0, stream,
                           W, C, (unsigned short*)d_ws);
        const int nblk = (ntok / TB) * NHEADS;   // 1024
        hipLaunchKernelGGL(vq_main, dim3(nblk), dim3(256), 0, stream,
                           x, (const unsigned short*)d_ws, T, out);
    } else {
        const int nblk = (ntok / 64) * NHEADS;   // 2048
        hipLaunchKernelGGL(vq_fwd_mfma, dim3(nblk), dim3(256), 0, stream,
                           x, W, C, T, out);
    }
}

// Round 8
// 78.886 us; speedup vs baseline: 2.6941x; 1.2505x over previous
//
#include <hip/hip_runtime.h>
#include <math.h>

#define NHEADS 16
#define HS     128
#define NOPT   512
#define TB     128      // tokens per block (4 waves x 32)
#define OC     32       // options per chunk
#define NCH    16       // chunks
#define EMB    2048
#define LOG2E  1.44269504088896340736f
#define THRD   11.0f    // defer-max threshold (log2 units)

typedef short bf16x8 __attribute__((ext_vector_type(8)));
typedef _Float16 f16x8 __attribute__((ext_vector_type(8)));
typedef unsigned short u16x8 __attribute__((ext_vector_type(8)));
typedef float f32x4 __attribute__((ext_vector_type(4)));
typedef float f32x16 __attribute__((ext_vector_type(16)));
typedef unsigned u32x4 __attribute__((ext_vector_type(4)));

__device__ __forceinline__ unsigned short f2bf(float f) {
    union { float f; unsigned u; } v; v.f = f;
    unsigned r = v.u + 0x7FFFu + ((v.u >> 16) & 1u);
    return (unsigned short)(r >> 16);
}
__device__ __forceinline__ float bf2f(unsigned short h) {
    union { unsigned u; float f; } v; v.u = ((unsigned)h) << 16;
    return v.f;
}
__device__ __forceinline__ unsigned short f2h(float f) {   // RNE f32->f16 bits
    const _Float16 h = (_Float16)f;
    return __builtin_bit_cast(unsigned short, h);
}
__device__ __forceinline__ void gll16(const void* gptr, void* lptr) {
    __builtin_amdgcn_global_load_lds(
        (const __attribute__((address_space(1))) void*)gptr,
        (__attribute__((address_space(3))) void*)lptr,
        16, 0, 0);
}
// packed f32x2 -> f16x2 (RTZ), bit layout identical to the verified cvt_pk path
__device__ __forceinline__ unsigned pkrtz(float lo, float hi) {
    unsigned r;
    asm("v_cvt_pkrtz_f16_f32 %0, %1, %2" : "=v"(r) : "v"(lo), "v"(hi));
    return r;
}
__device__ __forceinline__ void pl32swap(unsigned &a, unsigned &b) {
    asm volatile("v_permlane32_swap_b32 %0, %1" : "+v"(a), "+v"(b));
}
__device__ __forceinline__ f32x16 mfma32h(f16x8 a, f16x8 b, f32x16 c) {
    return __builtin_amdgcn_mfma_f32_32x32x16_f16(a, b, c, 0, 0, 0);
}

// ---------------- workspace image layout (ushorts, f16 bits) ----------------
// W': [h][c] chunk = 32 opt x 128 k f16, PRE-SCALED by invT*log2e,
//     row-swizzled col^((opt&15)<<3).                 (8 KB/chunk)
// C : [h][c] chunk = C^T 128 a x 32 opt f16, swizzled opt^(((a>>1)&3)<<3). (8 KB)
#define WCH    4096
#define CCH    4096
#define WS_C0  (NHEADS * NCH * WCH)                               // 2 MB worth
#define WS_TOTAL_BYTES ((size_t)(WS_C0 + NHEADS * NCH * CCH) * 2) // 4 MB

// ============ prep: f32 -> pre-swizzled f16 chunk images ============
__global__ __launch_bounds__(256) void vq_prep(const float* __restrict__ W,
                                               const float* __restrict__ C,
                                               const float* __restrict__ temp,
                                               unsigned short* __restrict__ ws)
{
    const int b = blockIdx.x, t = threadIdx.x;
    if (b < NHEADS * NCH) {                 // W chunk (scaled, single f16)
        const float scW = (1.0f / temp[0]) * LOG2E;
        const float* src = W + (size_t)b * OC * HS;
        unsigned short* dst = ws + (size_t)b * WCH;
        for (int k = 0; k < 16; ++k) {
            const int e = k * 256 + t;      // 4096 elems
            const int opt = e >> 7, col = e & 127;
            dst[opt * 128 + (col ^ ((opt & 15) << 3))] = f2h(src[e] * scW);
        }
    } else {                                // C chunk -> C^T[a][opt] f16
        const int b2 = b - NHEADS * NCH;
        const float* src = C + (size_t)b2 * OC * HS;
        unsigned short* dst = ws + WS_C0 + (size_t)b2 * CCH;
        for (int k = 0; k < 16; ++k) {
            const int e = k * 256 + t;
            const int opt = e >> 7, a = e & 127;
            dst[a * 32 + (opt ^ (((a >> 1) & 3) << 3))] = f2h(src[e]);
        }
    }
}

// ============ main: f16 swapped-QK 32x32 MFMA, online softmax, in-reg P ====
// f16 single-product QK (2^-11 precision; bf16 single failed at 0.133, /8 -> ok),
// f16 PV. Triple-buffered chunks, 2-ahead prefetch, counted vmcnt(4) + raw
// s_barrier: loads stay in flight across barriers (T4). x regs 64->32; no xlo.
__global__ __launch_bounds__(256, 3) void vq_main(
    const float* __restrict__ x, const unsigned short* __restrict__ ws,
    float* __restrict__ out)
{
    __shared__ unsigned short wbuf[3][WCH];   // 24 KB (tri-buffered W chunk)
    __shared__ unsigned short cbuf[3][CCH];   // 24 KB (tri-buffered C^T chunk)

    const int t = threadIdx.x, l = t & 63, w = t >> 6;
    const int la = l & 31, hf = l >> 5;
    const int b = blockIdx.x;
    const int head = ((b & 7) << 1) | ((b >> 3) & 1);   // 2 heads per XCD
    const int n0 = (b >> 4) * TB;

    const unsigned short* gwbase = ws + (size_t)(head * NCH) * WCH;
    const unsigned short* gcbase = ws + WS_C0 + (size_t)(head * NCH) * CCH;

    // ---- x row as f16 B-fragments (32 VGPR). Loads issued first so the
    //      compiler's x-waits leave the DMA below still in flight. ----
    f16x8 xf[8];
    {
        const float* xr = x + (size_t)(n0 + w * 32 + la) * EMB + head * HS + hf * 8;
        #pragma unroll
        for (int kb = 0; kb < 8; ++kb) {
            const float4 v0 = *(const float4*)(xr + kb * 16);
            const float4 v1 = *(const float4*)(xr + kb * 16 + 4);
            const float vv[8] = {v0.x, v0.y, v0.z, v0.w, v1.x, v1.y, v1.z, v1.w};
            u16x8 hh;
            #pragma unroll
            for (int j = 0; j < 8; ++j) hh[j] = f2h(vv[j]);
            xf[kb] = __builtin_bit_cast(f16x8, hh);
        }
    }

    // ---- prologue DMA: chunk 0 -> slot 0, chunk 1 -> slot 1 (8 loads) ----
    #pragma unroll
    for (int p = 0; p < 2; ++p) {
        const char* gw = (const char*)(gwbase + (size_t)p * WCH) + w * 2048 + l * 16;
        char* lw = (char*)&wbuf[p][0] + w * 2048;
        gll16(gw, lw); gll16(gw + 1024, lw + 1024);
        const char* gc = (const char*)(gcbase + (size_t)p * CCH) + w * 2048 + l * 16;
        char* lc = (char*)&cbuf[p][0] + w * 2048;
        gll16(gc, lc); gll16(gc + 1024, lc + 1024);
    }

    f32x16 O0 = (f32x16)0.0f, O1 = (f32x16)0.0f, O2 = (f32x16)0.0f, O3 = (f32x16)0.0f;
    float M = -1.0e30f, sacc = 0.0f;

    asm volatile("s_waitcnt vmcnt(4)" ::: "memory");   // chunk 0 landed; chunk 1 in flight
    __builtin_amdgcn_s_barrier();

    int bc = 0;   // current buffer slot
    for (int c = 0; c < NCH; ++c) {
        // ---- prefetch chunk c+2 into slot (bc+2)%3 (last read at iter c-1) ----
        if (c + 2 < NCH) {
            int bp = bc + 2; if (bp >= 3) bp -= 3;
            const char* gw = (const char*)(gwbase + (size_t)(c + 2) * WCH) + w * 2048 + l * 16;
            char* lw = (char*)&wbuf[bp][0] + w * 2048;
            gll16(gw, lw); gll16(gw + 1024, lw + 1024);
            const char* gc = (const char*)(gcbase + (size_t)(c + 2) * CCH) + w * 2048 + l * 16;
            char* lc = (char*)&cbuf[bp][0] + w * 2048;
            gll16(gc, lc); gll16(gc + 1024, lc + 1024);
        }

        // ---- QK^T swapped: S^T[opt][tok] = W' · x^T (single f16 product) ----
        f32x16 sa = (f32x16)0.0f, sb = (f32x16)0.0f;
        const unsigned short* wb = &wbuf[bc][0];
        #pragma unroll
        for (int kb = 0; kb < 8; ++kb) {
            const int idx = la * 128 + ((kb * 16 + hf * 8) ^ ((la & 15) << 3));
            const f16x8 wf = *(const f16x8*)&wb[idx];
            if (kb & 1) sb = mfma32h(wf, xf[kb], sb);
            else        sa = mfma32h(wf, xf[kb], sa);
        }
        const f32x16 S = sa + sb;   // log2 units (invT*log2e folded into W')

        // ---- online softmax (per token = per lane), tree reductions ----
        float m8[8];
        #pragma unroll
        for (int i = 0; i < 8; ++i) m8[i] = fmaxf(S[2 * i], S[2 * i + 1]);
        float m4a = fmaxf(m8[0], m8[1]), m4b = fmaxf(m8[2], m8[3]);
        float m4c = fmaxf(m8[4], m8[5]), m4d = fmaxf(m8[6], m8[7]);
        float cmax = fmaxf(fmaxf(m4a, m4b), fmaxf(m4c, m4d));
        cmax = fmaxf(cmax, __shfl_xor(cmax, 32));
        if (__any(cmax > M + THRD)) {          // rare rescale (defer-max, T13)
            const float Mn = fmaxf(M, cmax);
            const float fr = exp2f(M - Mn);    // first chunk: exp2(-1e30)=0
            M = Mn;
            sacc *= fr;
            #pragma unroll
            for (int q = 0; q < 16; ++q) {
                const int row = (q & 3) + 8 * (q >> 2) + 4 * hf;
                const float f = __shfl(fr, row);
                O0[q] *= f; O1[q] *= f; O2[q] *= f; O3[q] *= f;
            }
        }
        float pv[16];
        #pragma unroll
        for (int q = 0; q < 16; ++q) pv[q] = exp2f(S[q] - M);
        {   // tree sum
            float s8[8];
            #pragma unroll
            for (int i = 0; i < 8; ++i) s8[i] = pv[2 * i] + pv[2 * i + 1];
            sacc += ((s8[0] + s8[1]) + (s8[2] + s8[3])) +
                    ((s8[4] + s8[5]) + (s8[6] + s8[7]));
        }

        // ---- P -> f16 A-fragments fully in-register (T12, verified layout) ----
        unsigned pk0 = pkrtz(pv[0],  pv[1]),  pk1 = pkrtz(pv[2],  pv[3]);
        unsigned pk2 = pkrtz(pv[4],  pv[5]),  pk3 = pkrtz(pv[6],  pv[7]);
        unsigned pk4 = pkrtz(pv[8],  pv[9]),  pk5 = pkrtz(pv[10], pv[11]);
        unsigned pk6 = pkrtz(pv[12], pv[13]), pk7 = pkrtz(pv[14], pv[15]);
        pl32swap(pk0, pk2);
        pl32swap(pk1, pk3);
        pl32swap(pk4, pk6);
        pl32swap(pk5, pk7);
        const f16x8 pa0 = __builtin_bit_cast(f16x8, (u32x4){pk0, pk1, pk2, pk3});
        const f16x8 pa1 = __builtin_bit_cast(f16x8, (u32x4){pk4, pk5, pk6, pk7});

        // ---- PV: O += P · C (A=P regs, B=C^T LDS) ----
        const unsigned short* cb = &cbuf[bc][0];
        {
            const int a0 = la;
            const int sw0 = ((a0 >> 1) & 3) << 3;
            O0 = mfma32h(pa0, *(const f16x8*)&cb[a0 * 32 + ((hf * 8) ^ sw0)], O0);
            O0 = mfma32h(pa1, *(const f16x8*)&cb[a0 * 32 + ((16 + hf * 8) ^ sw0)], O0);
            const int a1 = 32 + la;
            const int sw1 = ((a1 >> 1) & 3) << 3;
            O1 = mfma32h(pa0, *(const f16x8*)&cb[a1 * 32 + ((hf * 8) ^ sw1)], O1);
            O1 = mfma32h(pa1, *(const f16x8*)&cb[a1 * 32 + ((16 + hf * 8) ^ sw1)], O1);
            const int a2 = 64 + la;
            const int sw2 = ((a2 >> 1) & 3) << 3;
            O2 = mfma32h(pa0, *(const f16x8*)&cb[a2 * 32 + ((hf * 8) ^ sw2)], O2);
            O2 = mfma32h(pa1, *(const f16x8*)&cb[a2 * 32 + ((16 + hf * 8) ^ sw2)], O2);
            const int a3 = 96 + la;
            const int sw3 = ((a3 >> 1) & 3) << 3;
            O3 = mfma32h(pa0, *(const f16x8*)&cb[a3 * 32 + ((hf * 8) ^ sw3)], O3);
            O3 = mfma32h(pa1, *(const f16x8*)&cb[a3 * 32 + ((16 + hf * 8) ^ sw3)], O3);
        }

        // ---- tail: ensure chunk c+1 landed (leave c+2 in flight), then barrier ----
        if (c < NCH - 2) { asm volatile("s_waitcnt vmcnt(4)" ::: "memory"); }
        else             { asm volatile("s_waitcnt vmcnt(0)" ::: "memory"); }
        __builtin_amdgcn_s_barrier();
        ++bc; if (bc >= 3) bc -= 3;
    }

    // ---- epilogue: normalize by 1/sum, coalesced stores ----
    const float stot = sacc + __shfl_xor(sacc, 32);
    const float rs = 1.0f / stot;
    #pragma unroll
    for (int q = 0; q < 16; ++q) {
        const int row = (q & 3) + 8 * (q >> 2) + 4 * hf;
        const float rq = __shfl(rs, row);
        float* op = out + (size_t)(n0 + w * 32 + row) * EMB + head * HS + la;
        op[0]  = O0[q] * rq;
        op[32] = O1[q] * rq;
        op[64] = O2[q] * rq;
        op[96] = O3[q] * rq;
    }
}

// ============ fallback (Round-2 kernel, no workspace needed) ============
__global__ __launch_bounds__(256, 2) void vq_fwd_mfma(
    const float* __restrict__ x, const float* __restrict__ W,
    const float* __restrict__ C, const float* __restrict__ temp,
    float* __restrict__ out)
{
    __shared__ unsigned short xh_lds[64 * HS];
    __shared__ unsigned short xl_lds[64 * HS];
    __shared__ unsigned short wst[2][64 * HS];
    __shared__ unsigned short p_lds[4][16 * 64];

    const int t = threadIdx.x, l = t & 63, w = t >> 6, lr = l & 15, lk = l >> 4;
    const int b = blockIdx.x;
    const int h = ((b & 7) << 1) | ((b >> 3) & 1);
    const int n0 = (b >> 4) * 64;
    const float invT = 1.0f / temp[0];

    #pragma unroll
    for (int kk = 0; kk < 4; ++kk) {
        const int g = t + 256 * kk;
        const int row = g >> 4, c8 = (g & 15) * 8;
        const float* src = x + (size_t)(n0 + row) * EMB + h * HS + c8;
        const float4 v0 = *(const float4*)src;
        const float4 v1 = *(const float4*)(src + 4);
        float vv[8] = {v0.x, v0.y, v0.z, v0.w, v1.x, v1.y, v1.z, v1.w};
        u16x8 hh, ll;
        #pragma unroll
        for (int j = 0; j < 8; ++j) {
            const unsigned short hb = f2bf(vv[j]);
            hh[j] = hb; ll[j] = f2bf(vv[j] - bf2f(hb));
        }
        const int idx = row * HS + (c8 ^ ((row & 7) << 3));
        *(u16x8*)&xh_lds[idx] = hh;
        *(u16x8*)&xl_lds[idx] = ll;
    }

    f32x4 acc[32];
    #pragma unroll
    for (int i = 0; i < 32; ++i) acc[i] = f32x4{0.f, 0.f, 0.f, 0.f};
    bf16x8 axh[4], axl[4];

    #pragma unroll
    for (int c = 0; c < 8; ++c) {
        if (c) __syncthreads();
        #pragma unroll
        for (int kk = 0; kk < 4; ++kk) {
            const int g = t + 256 * kk;
            const int row = g >> 4, c8 = (g & 15) * 8;
            const float* src = W + ((size_t)h * NOPT + c * 64 + row) * HS + c8;
            const float4 v0 = *(const float4*)src;
            const float4 v1 = *(const float4*)(src + 4);
            float vv[8] = {v0.x, v0.y, v0.z, v0.w, v1.x, v1.y, v1.z, v1.w};
            u16x8 hh, ll;
            #pragma unroll
            for (int j = 0; j < 8; ++j) {
                const unsigned short hb = f2bf(vv[j]);
                hh[j] = hb; ll[j] = f2bf(vv[j] - bf2f(hb));
            }
            const int idx = row * HS + (c8 ^ ((row & 7) << 3));
            *(u16x8*)&wst[0][idx] = hh;
            *(u16x8*)&wst[1][idx] = ll;
        }
        __syncthreads();
        if (c == 0) {
            const int arow = w * 16 + lr;
            #pragma unroll
            for (int ks = 0; ks < 4; ++ks) {
                const int ai = arow * HS + ((lk * 8 + ks * 32) ^ ((arow & 7) << 3));
                axh[ks] = *(const bf16x8*)&xh_lds[ai];
                axl[ks] = *(const bf16x8*)&xl_lds[ai];
            }
        }
        #pragma unroll
        for (int nt = 0; nt < 4; ++nt) {
            const int brow = nt * 16 + lr;
            #pragma unroll
            for (int ks = 0; ks < 4; ++ks) {
                const int bi = brow * HS + ((lk * 8 + ks * 32) ^ ((brow & 7) << 3));
                const bf16x8 bh = *(const bf16x8*)&wst[0][bi];
                const bf16x8 bl = *(const bf16x8*)&wst[1][bi];
                acc[c*4+nt] = __builtin_amdgcn_mfma_f32_16x16x32_bf16(axh[ks], bh, acc[c*4+nt], 0, 0, 0);
                acc[c*4+nt] = __builtin_amdgcn_mfma_f32_16x16x32_bf16(axl[ks], bh, acc[c*4+nt], 0, 0, 0);
                acc[c*4+nt] = __builtin_amdgcn_mfma_f32_16x16x32_bf16(axh[ks], bl, acc[c*4+nt], 0, 0, 0);
            }
        }
    }

    float mx[4], rsn[4];
    #pragma unroll
    for (int r = 0; r < 4; ++r) {
        float m = -3.0e38f;
        #pragma unroll
        for (int i = 0; i < 32; ++i) m = fmaxf(m, acc[i][r]);
        m *= invT;
        #pragma unroll
        for (int s = 1; s < 16; s <<= 1) m = fmaxf(m, __shfl_xor(m, s));
        float sum = 0.f;
        #pragma unroll
        for (int i = 0; i < 32; ++i) sum += exp2f((acc[i][r] * invT - m) * LOG2E);
        #pragma unroll
        for (int s = 1; s < 16; s <<= 1) sum += __shfl_xor(sum, s);
        mx[r] = m; rsn[r] = 1.0f / sum;
    }

    f32x4 oacc[8];
    #pragma unroll
    for (int i = 0; i < 8; ++i) oacc[i] = f32x4{0.f, 0.f, 0.f, 0.f};
    const int pr_ = t & 31, ag = t >> 5;
    #pragma unroll
    for (int c = 0; c < 8; ++c) {
        __syncthreads();
        {
            const float* c0p = C + ((size_t)h * NOPT + c * 64 + 2 * pr_) * HS + ag * 16;
            float va[16], vb[16];
            #pragma unroll
            for (int q = 0; q < 4; ++q) {
                const float4 u0 = ((const float4*)c0p)[q];
                const float4 u1 = ((const float4*)(c0p + HS))[q];
                va[q*4+0] = u0.x; va[q*4+1] = u0.y; va[q*4+2] = u0.z; va[q*4+3] = u0.w;
                vb[q*4+0] = u1.x; vb[q*4+1] = u1.y; vb[q*4+2] = u1.z; vb[q*4+3] = u1.w;
            }
            unsigned* ct32 = (unsigned*)&wst[0][0];
            #pragma unroll
            for (int j = 0; j < 16; ++j) {
                const int a = ag * 16 + j;
                const unsigned pkv = (unsigned)f2bf(va[j]) | ((unsigned)f2bf(vb[j]) << 16);
                ct32[a * 32 + (pr_ ^ ((a & 7) << 2))] = pkv;
            }
        }
        #pragma unroll
        for (int nt = 0; nt < 4; ++nt) {
            #pragma unroll
            for (int r = 0; r < 4; ++r) {
                const float p = exp2f((acc[c*4+nt][r] * invT - mx[r]) * LOG2E);
                const int prow = lk * 4 + r;
                const int pcol = nt * 16 + lr;
                p_lds[w][prow * 64 + (pcol ^ ((prow & 7) << 3))] = f2bf(p);
            }
        }
        __syncthreads();
        #pragma unroll
        for (int ks = 0; ks < 2; ++ks) {
            const int ai = lr * 64 + ((lk * 8 + ks * 32) ^ ((lr & 7) << 3));
            const bf16x8 pa = *(const bf16x8*)&p_lds[w][ai];
            #pragma unroll
            for (int nt = 0; nt < 8; ++nt) {
                const int brow = nt * 16 + lr;
                const int bi = brow * 64 + ((lk * 8 + ks * 32) ^ ((brow & 7) << 3));
                const bf16x8 cbv = *(const bf16x8*)&wst[0][bi];
                oacc[nt] = __builtin_amdgcn_mfma_f32_16x16x32_bf16(pa, cbv, oacc[nt], 0, 0, 0);
            }
        }
    }

    #pragma unroll
    for (int nt = 0; nt < 8; ++nt) {
        #pragma unroll
        for (int r = 0; r < 4; ++r) {
            const int tok = n0 + w * 16 + lk * 4 + r;
            out[(size_t)tok * EMB + h * HS + nt * 16 + lr] = oacc[nt][r] * rsn[r];
        }
    }
}

extern "C" void kernel_launch(void* const* d_in, const int* in_sizes, int n_in,
                              void* d_out, int out_size, void* d_ws, size_t ws_size,
                              hipStream_t stream) {
    const float* x = (const float*)d_in[0];
    const float* W = (const float*)d_in[1];
    const float* C = (const float*)d_in[2];
    const float* T = (const float*)d_in[3];
    float* out     = (float*)d_out;

    const int ntok = in_sizes[0] / EMB;   // 8192

    if (ws_size >= WS_TOTAL_BYTES) {
        hipLaunchKernelGGL(vq_prep, dim3(NHEADS * NCH * 2), dim3(256), 0, stream,
                           W, C, T, (unsigned short*)d_ws);
        const int nblk = (ntok / TB) * NHEADS;   // 1024
        hipLaunchKernelGGL(vq_main, dim3(nblk), dim3(256), 0, stream,
                           x, (const unsigned short*)d_ws, out);
    } else {
        const int nblk = (ntok / 64) * NHEADS;   // 2048
        hipLaunchKernelGGL(vq_fwd_mfma, dim3(nblk), dim3(256), 0, stream,
                           x, W, C, T, out);
    }
}